// Round 3
// baseline (37940.228 us; speedup 1.0000x reference)
//
#include <hip/hip_runtime.h>
#include <math.h>

#define Bb   256
#define Tt   512
#define INn  64
#define Hh   512
#define OUTn 96
#define NWG  256
#define TPB  512
#define SP   (Hh*Bb)   // one state plane in floats
#define RSTRIDE 36     // reduction row stride (floats), 16B-aligned

struct Params {
  const float *Xt;          // [T][IN][B]
  float *H0, *H1;           // [2][H][B] each (ping-pong)
  unsigned int *bar;        // bar[0]=cnt, bar[1]=gen
  const float *Wih0,*Whh0,*bih0,*bhh0,*Wih1,*Whh1,*bih1,*bhh1;
  const float *dWih0,*dWhh0,*dbih0,*dbhh0,*dWih1,*dWhh1,*dbih1,*dbhh1;
  const float *projW,*projb;
  float *out;               // [B][OUT]
};

__device__ __forceinline__ float sigm(float x){ return 1.0f/(1.0f + expf(-x)); }

__device__ __forceinline__ void gridbar(unsigned int* bar) {
  __syncthreads();
  if (threadIdx.x == 0) {
    __threadfence();  // release our writes to device scope
    unsigned int g   = __hip_atomic_load(&bar[1], __ATOMIC_RELAXED, __HIP_MEMORY_SCOPE_AGENT);
    unsigned int old = __hip_atomic_fetch_add(&bar[0], 1u, __ATOMIC_ACQ_REL, __HIP_MEMORY_SCOPE_AGENT);
    if (old == NWG - 1u) {
      __hip_atomic_store(&bar[0], 0u,     __ATOMIC_RELAXED, __HIP_MEMORY_SCOPE_AGENT);
      __hip_atomic_store(&bar[1], g + 1u, __ATOMIC_RELEASE, __HIP_MEMORY_SCOPE_AGENT);
    } else {
      while (__hip_atomic_load(&bar[1], __ATOMIC_RELAXED, __HIP_MEMORY_SCOPE_AGENT) == g)
        __builtin_amdgcn_s_sleep(2);
    }
    __threadfence();  // acquire
  }
  __syncthreads();
}

// Transpose inputs [B][T][IN] -> Xt [T][IN][B]
__global__ void __launch_bounds__(256) xpose(const float* __restrict__ X, float* __restrict__ Xt) {
  __shared__ float tile[64][65];
  const int t = blockIdx.x;
  const int l = threadIdx.x & 63;
  const int r = threadIdx.x >> 6;   // 0..3
  for (int qd = 0; qd < 4; ++qd) {
    #pragma unroll
    for (int rep = 0; rep < 16; ++rep) {
      int bl = rep*4 + r;
      tile[bl][l] = X[(size_t)(qd*64 + bl)*(Tt*INn) + (size_t)t*INn + l];
    }
    __syncthreads();
    #pragma unroll
    for (int rep = 0; rep < 16; ++rep) {
      int i = rep*4 + r;
      Xt[(size_t)t*(INn*Bb) + (size_t)i*Bb + qd*64 + l] = tile[l][i];
    }
    __syncthreads();
  }
}

// Persistent cooperative kernel.
// WG w owns hidden units {2w, 2w+1}. Thread layout (512 threads):
//   bq = tid&63        batch-quad id; thread handles batches 4*bq .. 4*bq+3
//   h  = (tid>>6)&1    which of the 2 units
//   kh = tid>>7        K-split 0..3; each handles 128 of the 512 K-rows
// kh>0 threads write partial gate sums to LDS; kh==0 reduces, applies
// activations, owns c-state, stores h-planes (all float4, consecutive b).
__global__ void __launch_bounds__(TPB, 2) lstm_main(Params P) {
  __shared__ float WA[512][16];  // enc: [k][h*8 + (0..3: Wih1 ifgo | 4..7: Whh0 ifgo)]
                                 // dec: [k][h*8 + (0..3: dWih1    | 4..7: dWhh1)]
  __shared__ float WB[512][8];   // enc: [k][h*4+g] Whh1 ; dec: dWhh0
  __shared__ float WX[64][8];    // enc: [k][h*4+g] Wih0
  __shared__ float BS[16];       // combined biases, same col layout as WA
  __shared__ float PW[Hh];       // proj_W
  __shared__ float WXD[8];       // dec_Wih0 column
  __shared__ float PBs;          // proj_b
  __shared__ float RED[3][128][RSTRIDE];  // K-split partials

  const int tid = threadIdx.x;
  const int w   = blockIdx.x;
  const int bq  = tid & 63;
  const int h   = (tid >> 6) & 1;
  const int kh  = tid >> 7;          // 0..3
  const int j   = 2*w + h;
  const int h8  = h*8, h4 = h*4;
  const int slot = h*64 + bq;        // 0..127
  const int b4  = 4*bq;              // first owned batch

  // ---------------- encoder weight load ----------------
  for (int e = tid; e < 512*16; e += TPB) {
    int k = e >> 4, c = e & 15, hh = c >> 3, s = c & 7;
    int unit = 2*w + hh;
    WA[k][c] = (s < 4) ? P.Wih1[(size_t)(s*Hh + unit)*Hh + k]
                       : P.Whh0[(size_t)((s-4)*Hh + unit)*Hh + k];
  }
  for (int e = tid; e < 512*8; e += TPB) {
    int k = e >> 3, c = e & 7, hh = c >> 2, g = c & 3;
    WB[k][c] = P.Whh1[(size_t)(g*Hh + 2*w + hh)*Hh + k];
  }
  for (int e = tid; e < 64*8; e += TPB) {
    int k = e >> 3, c = e & 7, hh = c >> 2, g = c & 3;
    WX[k][c] = P.Wih0[(size_t)(g*Hh + 2*w + hh)*INn + k];
  }
  if (tid < 16) {
    int c = tid, hh = c >> 3, s = c & 7;
    int unit = 2*w + hh;
    BS[c] = (s < 4) ? (P.bih1[s*Hh+unit] + P.bhh1[s*Hh+unit])
                    : (P.bih0[(s-4)*Hh+unit] + P.bhh0[(s-4)*Hh+unit]);
  }
  __syncthreads();

  float c0[4] = {0,0,0,0}, c1[4] = {0,0,0,0};

  // ---------------- encoder phases ----------------
  for (int p = -1; p <= 511; ++p) {
    float z1i[4], z1f[4], z1g[4], z1o[4];
    float z0i[4], z0f[4], z0g[4], z0o[4];
    #pragma unroll
    for (int m = 0; m < 4; ++m) {
      z1i[m] = (kh==0) ? BS[h8+0] : 0.f; z1f[m] = (kh==0) ? BS[h8+1] : 0.f;
      z1g[m] = (kh==0) ? BS[h8+2] : 0.f; z1o[m] = (kh==0) ? BS[h8+3] : 0.f;
      z0i[m] = (kh==0) ? BS[h8+4] : 0.f; z0f[m] = (kh==0) ? BS[h8+5] : 0.f;
      z0g[m] = (kh==0) ? BS[h8+6] : 0.f; z0o[m] = (kh==0) ? BS[h8+7] : 0.f;
    }
    const float* __restrict__ h0in = P.H0 + (size_t)(p & 1)*SP + b4;       // h0(p)
    const float* __restrict__ h1in = P.H1 + (size_t)((p+1) & 1)*SP + b4;   // h1(p-1)
    const int kb = kh*128, ke = kb + 128;
    #pragma unroll 4
    for (int k = kb; k < ke; ++k) {
      const float4 w1 = *reinterpret_cast<const float4*>(&WA[k][h8]);
      const float4 w0 = *reinterpret_cast<const float4*>(&WA[k][h8+4]);
      const float4 wb = *reinterpret_cast<const float4*>(&WB[k][h4]);
      const float4 hv4 = *reinterpret_cast<const float4*>(&h0in[k*Bb]);
      const float4 gv4 = *reinterpret_cast<const float4*>(&h1in[k*Bb]);
      const float* hv = &hv4.x;
      const float* gv = &gv4.x;
      #pragma unroll
      for (int m = 0; m < 4; ++m) {
        z1i[m]=fmaf(w1.x,hv[m],z1i[m]); z1f[m]=fmaf(w1.y,hv[m],z1f[m]);
        z1g[m]=fmaf(w1.z,hv[m],z1g[m]); z1o[m]=fmaf(w1.w,hv[m],z1o[m]);
        z0i[m]=fmaf(w0.x,hv[m],z0i[m]); z0f[m]=fmaf(w0.y,hv[m],z0f[m]);
        z0g[m]=fmaf(w0.z,hv[m],z0g[m]); z0o[m]=fmaf(w0.w,hv[m],z0o[m]);
        z1i[m]=fmaf(wb.x,gv[m],z1i[m]); z1f[m]=fmaf(wb.y,gv[m],z1f[m]);
        z1g[m]=fmaf(wb.z,gv[m],z1g[m]); z1o[m]=fmaf(wb.w,gv[m],z1o[m]);
      }
    }
    { // x-part: 16 K-rows per kh group
      int tx = (p+1 < Tt) ? (p+1) : (Tt-1);
      const float* __restrict__ xin = P.Xt + (size_t)tx*(INn*Bb) + b4;
      #pragma unroll 4
      for (int k = kh*16; k < kh*16 + 16; ++k) {
        const float4 wv = *reinterpret_cast<const float4*>(&WX[k][h4]);
        const float4 xv4 = *reinterpret_cast<const float4*>(&xin[k*Bb]);
        const float* xv = &xv4.x;
        #pragma unroll
        for (int m = 0; m < 4; ++m) {
          z0i[m]=fmaf(wv.x,xv[m],z0i[m]); z0f[m]=fmaf(wv.y,xv[m],z0f[m]);
          z0g[m]=fmaf(wv.z,xv[m],z0g[m]); z0o[m]=fmaf(wv.w,xv[m],z0o[m]);
        }
      }
    }
    if (kh) {
      float* r = &RED[kh-1][slot][0];
      *reinterpret_cast<float4*>(&r[ 0]) = make_float4(z1i[0],z1i[1],z1i[2],z1i[3]);
      *reinterpret_cast<float4*>(&r[ 4]) = make_float4(z1f[0],z1f[1],z1f[2],z1f[3]);
      *reinterpret_cast<float4*>(&r[ 8]) = make_float4(z1g[0],z1g[1],z1g[2],z1g[3]);
      *reinterpret_cast<float4*>(&r[12]) = make_float4(z1o[0],z1o[1],z1o[2],z1o[3]);
      *reinterpret_cast<float4*>(&r[16]) = make_float4(z0i[0],z0i[1],z0i[2],z0i[3]);
      *reinterpret_cast<float4*>(&r[20]) = make_float4(z0f[0],z0f[1],z0f[2],z0f[3]);
      *reinterpret_cast<float4*>(&r[24]) = make_float4(z0g[0],z0g[1],z0g[2],z0g[3]);
      *reinterpret_cast<float4*>(&r[28]) = make_float4(z0o[0],z0o[1],z0o[2],z0o[3]);
    }
    __syncthreads();
    if (kh == 0) {
      #pragma unroll
      for (int t = 0; t < 3; ++t) {
        const float* r = &RED[t][slot][0];
        #pragma unroll
        for (int m = 0; m < 4; ++m) {
          z1i[m]+=r[ 0+m]; z1f[m]+=r[ 4+m]; z1g[m]+=r[ 8+m]; z1o[m]+=r[12+m];
          z0i[m]+=r[16+m]; z0f[m]+=r[20+m]; z0g[m]+=r[24+m]; z0o[m]+=r[28+m];
        }
      }
      if (p >= 0) {
        float* st = P.H1 + (size_t)(p & 1)*SP + (size_t)j*Bb + b4;
        float4 o;
        float* ov = &o.x;
        #pragma unroll
        for (int m = 0; m < 4; ++m) {
          c1[m] = sigm(z1f[m])*c1[m] + sigm(z1i[m])*tanhf(z1g[m]);
          ov[m] = sigm(z1o[m])*tanhf(c1[m]);
        }
        *reinterpret_cast<float4*>(st) = o;
      }
      if (p < 511) {
        float* st = P.H0 + (size_t)((p+1) & 1)*SP + (size_t)j*Bb + b4;
        float4 o;
        float* ov = &o.x;
        #pragma unroll
        for (int m = 0; m < 4; ++m) {
          c0[m] = sigm(z0f[m])*c0[m] + sigm(z0i[m])*tanhf(z0g[m]);
          ov[m] = sigm(z0o[m])*tanhf(c0[m]);
        }
        *reinterpret_cast<float4*>(st) = o;
      }
    }
    gridbar(P.bar);
  }

  // ---------------- decoder weight load ----------------
  for (int e = tid; e < 512*16; e += TPB) {
    int k = e >> 4, c = e & 15, hh = c >> 3, s = c & 7;
    int unit = 2*w + hh;
    WA[k][c] = (s < 4) ? P.dWih1[(size_t)(s*Hh + unit)*Hh + k]
                       : P.dWhh1[(size_t)((s-4)*Hh + unit)*Hh + k];
  }
  for (int e = tid; e < 512*8; e += TPB) {
    int k = e >> 3, c = e & 7, hh = c >> 2, g = c & 3;
    WB[k][c] = P.dWhh0[(size_t)(g*Hh + 2*w + hh)*Hh + k];
  }
  if (tid < 8) {
    int c = tid, hh = c >> 2, g = c & 3;
    WXD[c] = P.dWih0[g*Hh + 2*w + hh];
  }
  if (tid >= 16 && tid < 32) {
    int c = tid - 16, hh = c >> 3, s = c & 7;
    int unit = 2*w + hh;
    BS[c] = (s < 4) ? (P.dbih1[s*Hh+unit] + P.dbhh1[s*Hh+unit])
                    : (P.dbih0[(s-4)*Hh+unit] + P.dbhh0[(s-4)*Hh+unit]);
  }
  for (int k = tid; k < Hh; k += TPB) PW[k] = P.projW[k];
  if (tid == 0) PBs = P.projb[0];
  __syncthreads();

  // ---------------- decoder ----------------
  for (int q = 0; q < OUTn; ++q) {
    // ---- phase A: cell0d(q). x(q) = (q==0) ? 0 : proj(h1d(q-1)) ----
    float xq[4] = {0,0,0,0};
    if (kh == 0 && q > 0) {
      const float* __restrict__ h1p = P.H1 + (size_t)((q+1)&1)*SP + b4;
      float acc[4] = {PBs, PBs, PBs, PBs};
      #pragma unroll 4
      for (int k = 0; k < Hh; ++k) {
        float pw = PW[k];
        const float4 hp4 = *reinterpret_cast<const float4*>(&h1p[k*Bb]);
        const float* hp = &hp4.x;
        #pragma unroll
        for (int m = 0; m < 4; ++m) acc[m] = fmaf(pw, hp[m], acc[m]);
      }
      #pragma unroll
      for (int m = 0; m < 4; ++m) xq[m] = acc[m];
      if (w == 0 && h == 0) {
        #pragma unroll
        for (int m = 0; m < 4; ++m) P.out[(size_t)(b4 + m)*OUTn + (q-1)] = xq[m];
      }
    }
    float zi[4], zf[4], zg[4], zo[4];
    #pragma unroll
    for (int m = 0; m < 4; ++m) {
      zi[m] = (kh==0) ? fmaf(WXD[h4+0], xq[m], BS[h8+4]) : 0.f;
      zf[m] = (kh==0) ? fmaf(WXD[h4+1], xq[m], BS[h8+5]) : 0.f;
      zg[m] = (kh==0) ? fmaf(WXD[h4+2], xq[m], BS[h8+6]) : 0.f;
      zo[m] = (kh==0) ? fmaf(WXD[h4+3], xq[m], BS[h8+7]) : 0.f;
    }
    {
      const float* __restrict__ h0p = P.H0 + (size_t)((q+1)&1)*SP + b4;  // h0d(q-1)
      const int kb = kh*128, ke = kb + 128;
      #pragma unroll 4
      for (int k = kb; k < ke; ++k) {
        const float4 wv = *reinterpret_cast<const float4*>(&WB[k][h4]);
        const float4 hv4 = *reinterpret_cast<const float4*>(&h0p[k*Bb]);
        const float* hv = &hv4.x;
        #pragma unroll
        for (int m = 0; m < 4; ++m) {
          zi[m]=fmaf(wv.x,hv[m],zi[m]); zf[m]=fmaf(wv.y,hv[m],zf[m]);
          zg[m]=fmaf(wv.z,hv[m],zg[m]); zo[m]=fmaf(wv.w,hv[m],zo[m]);
        }
      }
    }
    if (kh) {
      float* r = &RED[kh-1][slot][0];
      *reinterpret_cast<float4*>(&r[ 0]) = make_float4(zi[0],zi[1],zi[2],zi[3]);
      *reinterpret_cast<float4*>(&r[ 4]) = make_float4(zf[0],zf[1],zf[2],zf[3]);
      *reinterpret_cast<float4*>(&r[ 8]) = make_float4(zg[0],zg[1],zg[2],zg[3]);
      *reinterpret_cast<float4*>(&r[12]) = make_float4(zo[0],zo[1],zo[2],zo[3]);
    }
    __syncthreads();
    if (kh == 0) {
      #pragma unroll
      for (int t = 0; t < 3; ++t) {
        const float* r = &RED[t][slot][0];
        #pragma unroll
        for (int m = 0; m < 4; ++m) { zi[m]+=r[m]; zf[m]+=r[4+m]; zg[m]+=r[8+m]; zo[m]+=r[12+m]; }
      }
      float* st = P.H0 + (size_t)(q&1)*SP + (size_t)j*Bb + b4;
      float4 o;
      float* ov = &o.x;
      #pragma unroll
      for (int m = 0; m < 4; ++m) {
        c0[m] = sigm(zf[m])*c0[m] + sigm(zi[m])*tanhf(zg[m]);
        ov[m] = sigm(zo[m])*tanhf(c0[m]);
      }
      *reinterpret_cast<float4*>(st) = o;
    }
    gridbar(P.bar);

    // ---- phase B: cell1d(q) ----
    float yi[4], yf[4], yg[4], yo[4];
    #pragma unroll
    for (int m = 0; m < 4; ++m) {
      yi[m] = (kh==0) ? BS[h8+0] : 0.f; yf[m] = (kh==0) ? BS[h8+1] : 0.f;
      yg[m] = (kh==0) ? BS[h8+2] : 0.f; yo[m] = (kh==0) ? BS[h8+3] : 0.f;
    }
    {
      const float* __restrict__ h0c = P.H0 + (size_t)(q&1)*SP + b4;        // h0d(q)
      const float* __restrict__ h1q = P.H1 + (size_t)((q+1)&1)*SP + b4;    // h1d(q-1)
      const int kb = kh*128, ke = kb + 128;
      #pragma unroll 4
      for (int k = kb; k < ke; ++k) {
        const float4 w1 = *reinterpret_cast<const float4*>(&WA[k][h8]);
        const float4 w2 = *reinterpret_cast<const float4*>(&WA[k][h8+4]);
        const float4 av4 = *reinterpret_cast<const float4*>(&h0c[k*Bb]);
        const float4 dv4 = *reinterpret_cast<const float4*>(&h1q[k*Bb]);
        const float* av = &av4.x;
        const float* dv = &dv4.x;
        #pragma unroll
        for (int m = 0; m < 4; ++m) {
          yi[m]=fmaf(w1.x,av[m],yi[m]); yf[m]=fmaf(w1.y,av[m],yf[m]);
          yg[m]=fmaf(w1.z,av[m],yg[m]); yo[m]=fmaf(w1.w,av[m],yo[m]);
          yi[m]=fmaf(w2.x,dv[m],yi[m]); yf[m]=fmaf(w2.y,dv[m],yf[m]);
          yg[m]=fmaf(w2.z,dv[m],yg[m]); yo[m]=fmaf(w2.w,dv[m],yo[m]);
        }
      }
    }
    if (kh) {
      float* r = &RED[kh-1][slot][0];
      *reinterpret_cast<float4*>(&r[ 0]) = make_float4(yi[0],yi[1],yi[2],yi[3]);
      *reinterpret_cast<float4*>(&r[ 4]) = make_float4(yf[0],yf[1],yf[2],yf[3]);
      *reinterpret_cast<float4*>(&r[ 8]) = make_float4(yg[0],yg[1],yg[2],yg[3]);
      *reinterpret_cast<float4*>(&r[12]) = make_float4(yo[0],yo[1],yo[2],yo[3]);
    }
    __syncthreads();
    if (kh == 0) {
      #pragma unroll
      for (int t = 0; t < 3; ++t) {
        const float* r = &RED[t][slot][0];
        #pragma unroll
        for (int m = 0; m < 4; ++m) { yi[m]+=r[m]; yf[m]+=r[4+m]; yg[m]+=r[8+m]; yo[m]+=r[12+m]; }
      }
      float* st = P.H1 + (size_t)(q&1)*SP + (size_t)j*Bb + b4;
      float4 o;
      float* ov = &o.x;
      #pragma unroll
      for (int m = 0; m < 4; ++m) {
        c1[m] = sigm(yf[m])*c1[m] + sigm(yi[m])*tanhf(yg[m]);
        ov[m] = sigm(yo[m])*tanhf(c1[m]);
      }
      *reinterpret_cast<float4*>(st) = o;
    }
    gridbar(P.bar);
  }

  // ---- final y(OUT-1) ----
  if (kh == 0 && w == 0 && h == 0) {
    const float* __restrict__ h1f = P.H1 + (size_t)((OUTn-1)&1)*SP + b4;
    float acc[4] = {PBs, PBs, PBs, PBs};
    #pragma unroll 4
    for (int k = 0; k < Hh; ++k) {
      float pw = PW[k];
      const float4 hp4 = *reinterpret_cast<const float4*>(&h1f[k*Bb]);
      const float* hp = &hp4.x;
      #pragma unroll
      for (int m = 0; m < 4; ++m) acc[m] = fmaf(pw, hp[m], acc[m]);
    }
    #pragma unroll
    for (int m = 0; m < 4; ++m) P.out[(size_t)(b4 + m)*OUTn + (OUTn-1)] = acc[m];
  }
}

extern "C" void kernel_launch(void* const* d_in, const int* in_sizes, int n_in,
                              void* d_out, int out_size, void* d_ws, size_t ws_size,
                              hipStream_t stream) {
  Params P;
  const float* X = (const float*)d_in[0];
  P.Wih0  = (const float*)d_in[1];  P.Whh0  = (const float*)d_in[2];
  P.bih0  = (const float*)d_in[3];  P.bhh0  = (const float*)d_in[4];
  P.Wih1  = (const float*)d_in[5];  P.Whh1  = (const float*)d_in[6];
  P.bih1  = (const float*)d_in[7];  P.bhh1  = (const float*)d_in[8];
  P.dWih0 = (const float*)d_in[9];  P.dWhh0 = (const float*)d_in[10];
  P.dbih0 = (const float*)d_in[11]; P.dbhh0 = (const float*)d_in[12];
  P.dWih1 = (const float*)d_in[13]; P.dWhh1 = (const float*)d_in[14];
  P.dbih1 = (const float*)d_in[15]; P.dbhh1 = (const float*)d_in[16];
  P.projW = (const float*)d_in[17]; P.projb = (const float*)d_in[18];

  float* ws = (float*)d_ws;
  P.bar = (unsigned int*)ws;            // 256 B reserved
  P.H0  = ws + 64;                      // [2][H][B]
  P.H1  = ws + 64 + 2*SP;               // [2][H][B]
  float* Xt = ws + 64 + 4*SP;           // [T][IN][B]
  P.Xt  = Xt;
  P.out = (float*)d_out;

  hipMemsetAsync(d_ws, 0, (size_t)(64 + 4*SP)*sizeof(float), stream);
  hipLaunchKernelGGL(xpose, dim3(Tt), dim3(256), 0, stream, X, Xt);

  void* args[] = { &P };
  hipLaunchCooperativeKernel((void*)lstm_main, dim3(NWG), dim3(TPB), args, 0, stream);
}

// Round 4
// 28419.617 us; speedup vs baseline: 1.3350x; 1.3350x over previous
//
#include <hip/hip_runtime.h>
#include <math.h>

#define Bb   256
#define Tt   512
#define INn  64
#define Hh   512
#define OUTn 96
#define NWG  256
#define TPB  512
#define SP   (Hh*Bb)   // one state plane in floats
#define RSTRIDE 36     // reduction row stride (floats), 16B-aligned
#define HDR  8192      // ws header dwords: flags[256*16] + rel @4096, padded

struct Params {
  const float *Xt;          // [T][IN][B]
  float *H0, *H1;           // [2][H][B] each (ping-pong)
  unsigned int *flags;      // [NWG][16] padded arrival flags
  unsigned int *rel;        // single release word
  const float *Wih0,*Whh0,*bih0,*bhh0,*Wih1,*Whh1,*bih1,*bhh1;
  const float *dWih0,*dWhh0,*dbih0,*dbhh0,*dWih1,*dWhh1,*dbih1,*dbhh1;
  const float *projW,*projb;
  float *out;               // [B][OUT]
};

__device__ __forceinline__ float sigm(float x){ return 1.0f/(1.0f + expf(-x)); }

// Contention-free grid barrier: per-WG padded arrival flags + single release
// word. WG0 is the checker (threads 0..255 poll one flag each). Fence pattern
// identical to the proven atomic barrier (tid0 __threadfence = block-wide L1
// invalidate on CDNA). Ping-pong planes tolerate the 1-phase lookahead.
__device__ __forceinline__ void gridbar(unsigned int* flags, unsigned int* rel,
                                        unsigned int g) {
  __syncthreads();
  const int tid = threadIdx.x;
  if (blockIdx.x == 0) {
    if (tid > 0 && tid < NWG) {
      while (__hip_atomic_load(&flags[tid*16], __ATOMIC_RELAXED, __HIP_MEMORY_SCOPE_AGENT) < g)
        __builtin_amdgcn_s_sleep(1);
    }
    __syncthreads();
    if (tid == 0) {
      __threadfence();   // release our writes + acquire (L1 inv) for the block
      __hip_atomic_store(rel, g, __ATOMIC_RELEASE, __HIP_MEMORY_SCOPE_AGENT);
    }
    __syncthreads();
  } else {
    if (tid == 0) {
      __threadfence();   // release our writes
      __hip_atomic_store(&flags[blockIdx.x*16], g, __ATOMIC_RELEASE, __HIP_MEMORY_SCOPE_AGENT);
      while (__hip_atomic_load(rel, __ATOMIC_RELAXED, __HIP_MEMORY_SCOPE_AGENT) < g)
        __builtin_amdgcn_s_sleep(1);
      __threadfence();   // acquire (block-wide L1 invalidate)
    }
    __syncthreads();
  }
}

// Transpose inputs [B][T][IN] -> Xt [T][IN][B]
__global__ void __launch_bounds__(256) xpose(const float* __restrict__ X, float* __restrict__ Xt) {
  __shared__ float tile[64][65];
  const int t = blockIdx.x;
  const int l = threadIdx.x & 63;
  const int r = threadIdx.x >> 6;   // 0..3
  for (int qd = 0; qd < 4; ++qd) {
    #pragma unroll
    for (int rep = 0; rep < 16; ++rep) {
      int bl = rep*4 + r;
      tile[bl][l] = X[(size_t)(qd*64 + bl)*(Tt*INn) + (size_t)t*INn + l];
    }
    __syncthreads();
    #pragma unroll
    for (int rep = 0; rep < 16; ++rep) {
      int i = rep*4 + r;
      Xt[(size_t)t*(INn*Bb) + (size_t)i*Bb + qd*64 + l] = tile[l][i];
    }
    __syncthreads();
  }
}

// Persistent cooperative kernel.
// WG w owns hidden units {2w, 2w+1}. Thread layout (512 threads):
//   bq = tid&63        batch-quad id; thread handles batches 4*bq .. 4*bq+3
//   h  = (tid>>6)&1    which of the 2 units
//   kh = tid>>7        K-split 0..3; each handles 128 of the 512 K-rows
__global__ void __launch_bounds__(TPB, 2) lstm_main(Params P) {
  __shared__ float WA[512][16];
  __shared__ float WB[512][8];
  __shared__ float WX[64][8];
  __shared__ float BS[16];
  __shared__ float PW[Hh];
  __shared__ float WXD[8];
  __shared__ float PBs;
  __shared__ float RED[3][128][RSTRIDE];

  const int tid = threadIdx.x;
  const int w   = blockIdx.x;
  const int bq  = tid & 63;
  const int h   = (tid >> 6) & 1;
  const int kh  = tid >> 7;          // 0..3
  const int j   = 2*w + h;
  const int h8  = h*8, h4 = h*4;
  const int slot = h*64 + bq;        // 0..127
  const int b4  = 4*bq;              // first owned batch
  unsigned int bg = 1;               // barrier generation

  // ---------------- encoder weight load ----------------
  for (int e = tid; e < 512*16; e += TPB) {
    int k = e >> 4, c = e & 15, hh = c >> 3, s = c & 7;
    int unit = 2*w + hh;
    WA[k][c] = (s < 4) ? P.Wih1[(size_t)(s*Hh + unit)*Hh + k]
                       : P.Whh0[(size_t)((s-4)*Hh + unit)*Hh + k];
  }
  for (int e = tid; e < 512*8; e += TPB) {
    int k = e >> 3, c = e & 7, hh = c >> 2, g = c & 3;
    WB[k][c] = P.Whh1[(size_t)(g*Hh + 2*w + hh)*Hh + k];
  }
  for (int e = tid; e < 64*8; e += TPB) {
    int k = e >> 3, c = e & 7, hh = c >> 2, g = c & 3;
    WX[k][c] = P.Wih0[(size_t)(g*Hh + 2*w + hh)*INn + k];
  }
  if (tid < 16) {
    int c = tid, hh = c >> 3, s = c & 7;
    int unit = 2*w + hh;
    BS[c] = (s < 4) ? (P.bih1[s*Hh+unit] + P.bhh1[s*Hh+unit])
                    : (P.bih0[(s-4)*Hh+unit] + P.bhh0[(s-4)*Hh+unit]);
  }
  __syncthreads();

  float c0[4] = {0,0,0,0}, c1[4] = {0,0,0,0};

  // ---------------- encoder phases ----------------
  for (int p = -1; p <= 511; ++p) {
    float z1i[4], z1f[4], z1g[4], z1o[4];
    float z0i[4], z0f[4], z0g[4], z0o[4];
    #pragma unroll
    for (int m = 0; m < 4; ++m) {
      z1i[m] = (kh==0) ? BS[h8+0] : 0.f; z1f[m] = (kh==0) ? BS[h8+1] : 0.f;
      z1g[m] = (kh==0) ? BS[h8+2] : 0.f; z1o[m] = (kh==0) ? BS[h8+3] : 0.f;
      z0i[m] = (kh==0) ? BS[h8+4] : 0.f; z0f[m] = (kh==0) ? BS[h8+5] : 0.f;
      z0g[m] = (kh==0) ? BS[h8+6] : 0.f; z0o[m] = (kh==0) ? BS[h8+7] : 0.f;
    }
    const float* __restrict__ h0in = P.H0 + (size_t)(p & 1)*SP + b4;       // h0(p)
    const float* __restrict__ h1in = P.H1 + (size_t)((p+1) & 1)*SP + b4;   // h1(p-1)
    const int kb = kh*128, ke = kb + 128;
    #pragma unroll 4
    for (int k = kb; k < ke; ++k) {
      const float4 w1 = *reinterpret_cast<const float4*>(&WA[k][h8]);
      const float4 w0 = *reinterpret_cast<const float4*>(&WA[k][h8+4]);
      const float4 wb = *reinterpret_cast<const float4*>(&WB[k][h4]);
      const float4 hv4 = *reinterpret_cast<const float4*>(&h0in[k*Bb]);
      const float4 gv4 = *reinterpret_cast<const float4*>(&h1in[k*Bb]);
      const float* hv = &hv4.x;
      const float* gv = &gv4.x;
      #pragma unroll
      for (int m = 0; m < 4; ++m) {
        z1i[m]=fmaf(w1.x,hv[m],z1i[m]); z1f[m]=fmaf(w1.y,hv[m],z1f[m]);
        z1g[m]=fmaf(w1.z,hv[m],z1g[m]); z1o[m]=fmaf(w1.w,hv[m],z1o[m]);
        z0i[m]=fmaf(w0.x,hv[m],z0i[m]); z0f[m]=fmaf(w0.y,hv[m],z0f[m]);
        z0g[m]=fmaf(w0.z,hv[m],z0g[m]); z0o[m]=fmaf(w0.w,hv[m],z0o[m]);
        z1i[m]=fmaf(wb.x,gv[m],z1i[m]); z1f[m]=fmaf(wb.y,gv[m],z1f[m]);
        z1g[m]=fmaf(wb.z,gv[m],z1g[m]); z1o[m]=fmaf(wb.w,gv[m],z1o[m]);
      }
    }
    { // x-part: 16 K-rows per kh group
      int tx = (p+1 < Tt) ? (p+1) : (Tt-1);
      const float* __restrict__ xin = P.Xt + (size_t)tx*(INn*Bb) + b4;
      #pragma unroll 4
      for (int k = kh*16; k < kh*16 + 16; ++k) {
        const float4 wv = *reinterpret_cast<const float4*>(&WX[k][h4]);
        const float4 xv4 = *reinterpret_cast<const float4*>(&xin[k*Bb]);
        const float* xv = &xv4.x;
        #pragma unroll
        for (int m = 0; m < 4; ++m) {
          z0i[m]=fmaf(wv.x,xv[m],z0i[m]); z0f[m]=fmaf(wv.y,xv[m],z0f[m]);
          z0g[m]=fmaf(wv.z,xv[m],z0g[m]); z0o[m]=fmaf(wv.w,xv[m],z0o[m]);
        }
      }
    }
    if (kh) {
      float* r = &RED[kh-1][slot][0];
      *reinterpret_cast<float4*>(&r[ 0]) = make_float4(z1i[0],z1i[1],z1i[2],z1i[3]);
      *reinterpret_cast<float4*>(&r[ 4]) = make_float4(z1f[0],z1f[1],z1f[2],z1f[3]);
      *reinterpret_cast<float4*>(&r[ 8]) = make_float4(z1g[0],z1g[1],z1g[2],z1g[3]);
      *reinterpret_cast<float4*>(&r[12]) = make_float4(z1o[0],z1o[1],z1o[2],z1o[3]);
      *reinterpret_cast<float4*>(&r[16]) = make_float4(z0i[0],z0i[1],z0i[2],z0i[3]);
      *reinterpret_cast<float4*>(&r[20]) = make_float4(z0f[0],z0f[1],z0f[2],z0f[3]);
      *reinterpret_cast<float4*>(&r[24]) = make_float4(z0g[0],z0g[1],z0g[2],z0g[3]);
      *reinterpret_cast<float4*>(&r[28]) = make_float4(z0o[0],z0o[1],z0o[2],z0o[3]);
    }
    __syncthreads();
    if (kh == 0) {
      #pragma unroll
      for (int t = 0; t < 3; ++t) {
        const float* r = &RED[t][slot][0];
        #pragma unroll
        for (int m = 0; m < 4; ++m) {
          z1i[m]+=r[ 0+m]; z1f[m]+=r[ 4+m]; z1g[m]+=r[ 8+m]; z1o[m]+=r[12+m];
          z0i[m]+=r[16+m]; z0f[m]+=r[20+m]; z0g[m]+=r[24+m]; z0o[m]+=r[28+m];
        }
      }
      if (p >= 0) {
        float* st = P.H1 + (size_t)(p & 1)*SP + (size_t)j*Bb + b4;
        float4 o; float* ov = &o.x;
        #pragma unroll
        for (int m = 0; m < 4; ++m) {
          c1[m] = sigm(z1f[m])*c1[m] + sigm(z1i[m])*tanhf(z1g[m]);
          ov[m] = sigm(z1o[m])*tanhf(c1[m]);
        }
        *reinterpret_cast<float4*>(st) = o;
      }
      if (p < 511) {
        float* st = P.H0 + (size_t)((p+1) & 1)*SP + (size_t)j*Bb + b4;
        float4 o; float* ov = &o.x;
        #pragma unroll
        for (int m = 0; m < 4; ++m) {
          c0[m] = sigm(z0f[m])*c0[m] + sigm(z0i[m])*tanhf(z0g[m]);
          ov[m] = sigm(z0o[m])*tanhf(c0[m]);
        }
        *reinterpret_cast<float4*>(st) = o;
      }
    }
    gridbar(P.flags, P.rel, bg); ++bg;
  }

  // ---------------- decoder weight load ----------------
  for (int e = tid; e < 512*16; e += TPB) {
    int k = e >> 4, c = e & 15, hh = c >> 3, s = c & 7;
    int unit = 2*w + hh;
    WA[k][c] = (s < 4) ? P.dWih1[(size_t)(s*Hh + unit)*Hh + k]
                       : P.dWhh1[(size_t)((s-4)*Hh + unit)*Hh + k];
  }
  for (int e = tid; e < 512*8; e += TPB) {
    int k = e >> 3, c = e & 7, hh = c >> 2, g = c & 3;
    WB[k][c] = P.dWhh0[(size_t)(g*Hh + 2*w + hh)*Hh + k];
  }
  if (tid < 8) {
    int c = tid, hh = c >> 2, g = c & 3;
    WXD[c] = P.dWih0[g*Hh + 2*w + hh];
  }
  if (tid >= 16 && tid < 32) {
    int c = tid - 16, hh = c >> 3, s = c & 7;
    int unit = 2*w + hh;
    BS[c] = (s < 4) ? (P.dbih1[s*Hh+unit] + P.dbhh1[s*Hh+unit])
                    : (P.dbih0[(s-4)*Hh+unit] + P.dbhh0[(s-4)*Hh+unit]);
  }
  for (int k = tid; k < Hh; k += TPB) PW[k] = P.projW[k];
  if (tid == 0) PBs = P.projb[0];
  __syncthreads();

  // ---------------- decoder ----------------
  for (int q = 0; q < OUTn; ++q) {
    // ---- phase A: cell0d(q). x(q) = (q==0) ? 0 : proj(h1d(q-1)) ----
    float xq[4] = {0,0,0,0};
    if (kh == 0 && q > 0) {
      const float* __restrict__ h1p = P.H1 + (size_t)((q+1)&1)*SP + b4;
      float acc[4] = {PBs, PBs, PBs, PBs};
      #pragma unroll 4
      for (int k = 0; k < Hh; ++k) {
        float pw = PW[k];
        const float4 hp4 = *reinterpret_cast<const float4*>(&h1p[k*Bb]);
        const float* hp = &hp4.x;
        #pragma unroll
        for (int m = 0; m < 4; ++m) acc[m] = fmaf(pw, hp[m], acc[m]);
      }
      #pragma unroll
      for (int m = 0; m < 4; ++m) xq[m] = acc[m];
      if (w == 0 && h == 0) {
        #pragma unroll
        for (int m = 0; m < 4; ++m) P.out[(size_t)(b4 + m)*OUTn + (q-1)] = xq[m];
      }
    }
    float zi[4], zf[4], zg[4], zo[4];
    #pragma unroll
    for (int m = 0; m < 4; ++m) {
      zi[m] = (kh==0) ? fmaf(WXD[h4+0], xq[m], BS[h8+4]) : 0.f;
      zf[m] = (kh==0) ? fmaf(WXD[h4+1], xq[m], BS[h8+5]) : 0.f;
      zg[m] = (kh==0) ? fmaf(WXD[h4+2], xq[m], BS[h8+6]) : 0.f;
      zo[m] = (kh==0) ? fmaf(WXD[h4+3], xq[m], BS[h8+7]) : 0.f;
    }
    {
      const float* __restrict__ h0p = P.H0 + (size_t)((q+1)&1)*SP + b4;  // h0d(q-1)
      const int kb = kh*128, ke = kb + 128;
      #pragma unroll 4
      for (int k = kb; k < ke; ++k) {
        const float4 wv = *reinterpret_cast<const float4*>(&WB[k][h4]);
        const float4 hv4 = *reinterpret_cast<const float4*>(&h0p[k*Bb]);
        const float* hv = &hv4.x;
        #pragma unroll
        for (int m = 0; m < 4; ++m) {
          zi[m]=fmaf(wv.x,hv[m],zi[m]); zf[m]=fmaf(wv.y,hv[m],zf[m]);
          zg[m]=fmaf(wv.z,hv[m],zg[m]); zo[m]=fmaf(wv.w,hv[m],zo[m]);
        }
      }
    }
    if (kh) {
      float* r = &RED[kh-1][slot][0];
      *reinterpret_cast<float4*>(&r[ 0]) = make_float4(zi[0],zi[1],zi[2],zi[3]);
      *reinterpret_cast<float4*>(&r[ 4]) = make_float4(zf[0],zf[1],zf[2],zf[3]);
      *reinterpret_cast<float4*>(&r[ 8]) = make_float4(zg[0],zg[1],zg[2],zg[3]);
      *reinterpret_cast<float4*>(&r[12]) = make_float4(zo[0],zo[1],zo[2],zo[3]);
    }
    __syncthreads();
    if (kh == 0) {
      #pragma unroll
      for (int t = 0; t < 3; ++t) {
        const float* r = &RED[t][slot][0];
        #pragma unroll
        for (int m = 0; m < 4; ++m) { zi[m]+=r[m]; zf[m]+=r[4+m]; zg[m]+=r[8+m]; zo[m]+=r[12+m]; }
      }
      float* st = P.H0 + (size_t)(q&1)*SP + (size_t)j*Bb + b4;
      float4 o; float* ov = &o.x;
      #pragma unroll
      for (int m = 0; m < 4; ++m) {
        c0[m] = sigm(zf[m])*c0[m] + sigm(zi[m])*tanhf(zg[m]);
        ov[m] = sigm(zo[m])*tanhf(c0[m]);
      }
      *reinterpret_cast<float4*>(st) = o;
    }
    gridbar(P.flags, P.rel, bg); ++bg;

    // ---- phase B: cell1d(q) ----
    float yi[4], yf[4], yg[4], yo[4];
    #pragma unroll
    for (int m = 0; m < 4; ++m) {
      yi[m] = (kh==0) ? BS[h8+0] : 0.f; yf[m] = (kh==0) ? BS[h8+1] : 0.f;
      yg[m] = (kh==0) ? BS[h8+2] : 0.f; yo[m] = (kh==0) ? BS[h8+3] : 0.f;
    }
    {
      const float* __restrict__ h0c = P.H0 + (size_t)(q&1)*SP + b4;        // h0d(q)
      const float* __restrict__ h1q = P.H1 + (size_t)((q+1)&1)*SP + b4;    // h1d(q-1)
      const int kb = kh*128, ke = kb + 128;
      #pragma unroll 4
      for (int k = kb; k < ke; ++k) {
        const float4 w1 = *reinterpret_cast<const float4*>(&WA[k][h8]);
        const float4 w2 = *reinterpret_cast<const float4*>(&WA[k][h8+4]);
        const float4 av4 = *reinterpret_cast<const float4*>(&h0c[k*Bb]);
        const float4 dv4 = *reinterpret_cast<const float4*>(&h1q[k*Bb]);
        const float* av = &av4.x;
        const float* dv = &dv4.x;
        #pragma unroll
        for (int m = 0; m < 4; ++m) {
          yi[m]=fmaf(w1.x,av[m],yi[m]); yf[m]=fmaf(w1.y,av[m],yf[m]);
          yg[m]=fmaf(w1.z,av[m],yg[m]); yo[m]=fmaf(w1.w,av[m],yo[m]);
          yi[m]=fmaf(w2.x,dv[m],yi[m]); yf[m]=fmaf(w2.y,dv[m],yf[m]);
          yg[m]=fmaf(w2.z,dv[m],yg[m]); yo[m]=fmaf(w2.w,dv[m],yo[m]);
        }
      }
    }
    if (kh) {
      float* r = &RED[kh-1][slot][0];
      *reinterpret_cast<float4*>(&r[ 0]) = make_float4(yi[0],yi[1],yi[2],yi[3]);
      *reinterpret_cast<float4*>(&r[ 4]) = make_float4(yf[0],yf[1],yf[2],yf[3]);
      *reinterpret_cast<float4*>(&r[ 8]) = make_float4(yg[0],yg[1],yg[2],yg[3]);
      *reinterpret_cast<float4*>(&r[12]) = make_float4(yo[0],yo[1],yo[2],yo[3]);
    }
    __syncthreads();
    if (kh == 0) {
      #pragma unroll
      for (int t = 0; t < 3; ++t) {
        const float* r = &RED[t][slot][0];
        #pragma unroll
        for (int m = 0; m < 4; ++m) { yi[m]+=r[m]; yf[m]+=r[4+m]; yg[m]+=r[8+m]; yo[m]+=r[12+m]; }
      }
      float* st = P.H1 + (size_t)(q&1)*SP + (size_t)j*Bb + b4;
      float4 o; float* ov = &o.x;
      #pragma unroll
      for (int m = 0; m < 4; ++m) {
        c1[m] = sigm(yf[m])*c1[m] + sigm(yi[m])*tanhf(yg[m]);
        ov[m] = sigm(yo[m])*tanhf(c1[m]);
      }
      *reinterpret_cast<float4*>(st) = o;
    }
    gridbar(P.flags, P.rel, bg); ++bg;
  }

  // ---- final y(OUT-1) ----
  if (kh == 0 && w == 0 && h == 0) {
    const float* __restrict__ h1f = P.H1 + (size_t)((OUTn-1)&1)*SP + b4;
    float acc[4] = {PBs, PBs, PBs, PBs};
    #pragma unroll 4
    for (int k = 0; k < Hh; ++k) {
      float pw = PW[k];
      const float4 hp4 = *reinterpret_cast<const float4*>(&h1f[k*Bb]);
      const float* hp = &hp4.x;
      #pragma unroll
      for (int m = 0; m < 4; ++m) acc[m] = fmaf(pw, hp[m], acc[m]);
    }
    #pragma unroll
    for (int m = 0; m < 4; ++m) P.out[(size_t)(b4 + m)*OUTn + (OUTn-1)] = acc[m];
  }
}

extern "C" void kernel_launch(void* const* d_in, const int* in_sizes, int n_in,
                              void* d_out, int out_size, void* d_ws, size_t ws_size,
                              hipStream_t stream) {
  Params P;
  const float* X = (const float*)d_in[0];
  P.Wih0  = (const float*)d_in[1];  P.Whh0  = (const float*)d_in[2];
  P.bih0  = (const float*)d_in[3];  P.bhh0  = (const float*)d_in[4];
  P.Wih1  = (const float*)d_in[5];  P.Whh1  = (const float*)d_in[6];
  P.bih1  = (const float*)d_in[7];  P.bhh1  = (const float*)d_in[8];
  P.dWih0 = (const float*)d_in[9];  P.dWhh0 = (const float*)d_in[10];
  P.dbih0 = (const float*)d_in[11]; P.dbhh0 = (const float*)d_in[12];
  P.dWih1 = (const float*)d_in[13]; P.dWhh1 = (const float*)d_in[14];
  P.dbih1 = (const float*)d_in[15]; P.dbhh1 = (const float*)d_in[16];
  P.projW = (const float*)d_in[17]; P.projb = (const float*)d_in[18];

  float* ws = (float*)d_ws;
  P.flags = (unsigned int*)ws;          // [256][16] padded flags
  P.rel   = (unsigned int*)ws + 4096;   // release word (within HDR pad)
  P.H0  = ws + HDR;                     // [2][H][B]
  P.H1  = ws + HDR + 2*SP;              // [2][H][B]
  float* Xt = ws + HDR + 4*SP;          // [T][IN][B]
  P.Xt  = Xt;
  P.out = (float*)d_out;

  // zero flags/release + state ping-pong buffers (deterministic per launch)
  hipMemsetAsync(d_ws, 0, (size_t)(HDR + 4*SP)*sizeof(float), stream);
  hipLaunchKernelGGL(xpose, dim3(Tt), dim3(256), 0, stream, X, Xt);

  void* args[] = { &P };
  hipLaunchCooperativeKernel((void*)lstm_main, dim3(NWG), dim3(TPB), args, 0, stream);
}